// Round 4
// baseline (286.845 us; speedup 1.0000x reference)
//
#include <hip/hip_runtime.h>
#include <math.h>

#define NH    8
#define DIM   256
#define NQ    8400
#define BATCH 4
#define STOT  8400
#define MQ    (BATCH * NQ)   // 33600

typedef __attribute__((ext_vector_type(8))) short  s16x8;
typedef __attribute__((ext_vector_type(8))) unsigned short u16x8;
typedef __attribute__((ext_vector_type(4))) float  f32x4;

static __device__ __forceinline__ unsigned short f2bf(float x) {
    union { float f; unsigned u; } v; v.f = x;
    unsigned r = v.u + 0x7fffu + ((v.u >> 16) & 1u);   // RNE
    return (unsigned short)(r >> 16);
}
static __device__ __forceinline__ float bf2f(unsigned short h) {
    union { float f; unsigned u; } v; v.u = ((unsigned)h) << 16;
    return v.f;
}

// ---------------------------------------------------------------------------
// All weight transposes + bias concat in one launch. z=0..3 pick the matrix,
// z=4 does the bias.
__global__ __launch_bounds__(256) void prep_w(
    const float* __restrict__ W_val, const float* __restrict__ W_out,
    const float* __restrict__ W_off, const float* __restrict__ W_attn,
    const float* __restrict__ b_off, const float* __restrict__ b_attn,
    unsigned short* __restrict__ Wvt, unsigned short* __restrict__ Wot,
    unsigned short* __restrict__ Wch, unsigned short* __restrict__ Wcl,
    float* __restrict__ bcat)
{
    const int z = blockIdx.z;
    const int t = threadIdx.x;
    if (z == 4) {
        if (blockIdx.x == 0 && blockIdx.y == 0)
            for (int i = t; i < 288; i += 256)
                bcat[i] = (i < 192) ? b_off[i] : b_attn[i - 192];
        return;
    }
    const float* W; unsigned short *oH, *oL; int Nw, n0;
    switch (z) {
        case 0:  W = W_val;  oH = Wvt; oL = nullptr; Nw = 256; n0 = 0;   break;
        case 1:  W = W_out;  oH = Wot; oL = nullptr; Nw = 256; n0 = 0;   break;
        case 2:  W = W_off;  oH = Wch; oL = Wcl;     Nw = 192; n0 = 0;   break;
        default: W = W_attn; oH = Wch; oL = Wcl;     Nw = 96;  n0 = 192; break;
    }
    const int nb = blockIdx.x * 32, k0 = blockIdx.y * 32;
    if (nb >= Nw) return;
    __shared__ float tile[32][33];
    const int c = t & 31, r = t >> 5;
    #pragma unroll
    for (int i = 0; i < 4; ++i) {
        int k = k0 + r + i * 8, n = nb + c;
        tile[r + i * 8][c] = (n < Nw) ? W[(size_t)k * Nw + n] : 0.f;
    }
    __syncthreads();
    #pragma unroll
    for (int i = 0; i < 4; ++i) {
        int n = nb + r + i * 8, k = k0 + c;
        if (n < Nw) {
            float x = tile[c][r + i * 8];
            unsigned short h = f2bf(x);
            oH[(size_t)(n0 + n) * 256 + k] = h;
            if (oL) oL[(size_t)(n0 + n) * 256 + k] = f2bf(x - bf2f(h));
        }
    }
}

// ---------------------------------------------------------------------------
// z=0..3: feat transpose (all 3 levels) for batch z -> Abf[(b*8400+s)*256+k].
// z=4..7: query fp32 -> Qh/Ql bf16x2 planes (elementwise).
__global__ __launch_bounds__(256) void prep_af(
    const float* __restrict__ feat0, const float* __restrict__ feat1,
    const float* __restrict__ feat2, const float* __restrict__ query,
    unsigned short* __restrict__ Abf,
    unsigned short* __restrict__ Qh, unsigned short* __restrict__ Ql)
{
    const int z = blockIdx.z;
    const int t = threadIdx.x;
    if (z >= 4) {
        int lid = (z - 4) * 263 * 8 + blockIdx.x * 8 + blockIdx.y;
        size_t idx = (size_t)lid * 1024 + t * 4;
        if (idx < (size_t)MQ * 256) {
            float4 q = *(const float4*)(query + idx);
            float xs[4] = {q.x, q.y, q.z, q.w};
            ushort4 hv, lv;
            unsigned short h;
            h = f2bf(xs[0]); hv.x = h; lv.x = f2bf(xs[0] - bf2f(h));
            h = f2bf(xs[1]); hv.y = h; lv.y = f2bf(xs[1] - bf2f(h));
            h = f2bf(xs[2]); hv.z = h; lv.z = f2bf(xs[2] - bf2f(h));
            h = f2bf(xs[3]); hv.w = h; lv.w = f2bf(xs[3] - bf2f(h));
            *(ushort4*)(Qh + idx) = hv;
            *(ushort4*)(Ql + idx) = lv;
        }
        return;
    }
    const int b = z;
    const int s0 = blockIdx.x * 32, k0 = blockIdx.y * 32;
    const float* f0b = feat0 + (size_t)b * 256 * 6400;
    const float* f1b = feat1 + (size_t)b * 256 * 1600;
    const float* f2b = feat2 + (size_t)b * 256 * 400;
    __shared__ float tile[32][33];
    const int c = t & 31, r = t >> 5;
    #pragma unroll
    for (int i = 0; i < 4; ++i) {
        int rr = r + i * 8;
        int s = s0 + c;
        float v = 0.f;
        if (s < 8400) {
            const float* fp; int S, sl;
            if (s < 6400)      { fp = f0b; S = 6400; sl = s; }
            else if (s < 8000) { fp = f1b; S = 1600; sl = s - 6400; }
            else               { fp = f2b; S = 400;  sl = s - 8000; }
            v = fp[(size_t)(k0 + rr) * S + sl];
        }
        tile[rr][c] = v;
    }
    __syncthreads();
    #pragma unroll
    for (int i = 0; i < 4; ++i) {
        int s = s0 + r + i * 8, k = k0 + c;
        if (s < 8400)
            Abf[((size_t)b * 8400 + s) * 256 + k] = f2bf(tile[c][r + i * 8]);
    }
}

// ---------------------------------------------------------------------------
// Fused val-projection + offset/attn GEMM. blockIdx.x<2 -> val (plain bf16,
// bf16 head-plane epilogue); x>=2 -> raw (bf16x2 split, fp32 offsets + bf16
// attn epilogue). 128x128 tile, BK=32, 16x16x32 MFMA.
__global__ __launch_bounds__(256) void gemm_vr(
    const unsigned short* __restrict__ Abf,
    const unsigned short* __restrict__ Qh, const unsigned short* __restrict__ Ql,
    const unsigned short* __restrict__ Wvt,
    const unsigned short* __restrict__ Wch, const unsigned short* __restrict__ Wcl,
    const float* __restrict__ b_val, const float* __restrict__ bcat,
    unsigned short* __restrict__ valb, float* __restrict__ raw_off,
    unsigned short* __restrict__ attnb)
{
    __shared__ unsigned short Ah[128 * 40];
    __shared__ unsigned short Bs[128 * 40];
    __shared__ unsigned short Al[128 * 40];
    __shared__ unsigned short Bl2[128 * 40];

    const bool split = blockIdx.x >= 2;
    const int bn = split ? (blockIdx.x - 2) * 128 : blockIdx.x * 128;
    const int bm = blockIdx.y * 128;
    const int N = split ? 288 : 256;
    const unsigned short* Ag = split ? Qh : Abf;
    const unsigned short* Bg = split ? Wch : Wvt;

    const int t = threadIdx.x;
    const int lane = t & 63, w = t >> 6;
    const int wm = (w & 1) * 64, wn = (w >> 1) * 64;
    const int l15 = lane & 15, quad = lane >> 4;

    f32x4 acc[4][4];
    #pragma unroll
    for (int i = 0; i < 4; ++i)
        #pragma unroll
        for (int j = 0; j < 4; ++j)
            acc[i][j] = (f32x4){0.f, 0.f, 0.f, 0.f};

    for (int k0 = 0; k0 < 256; k0 += 32) {
        #pragma unroll
        for (int cc = 0; cc < 2; ++cc) {
            int cid = t + cc * 256;
            int r = cid >> 2, s = cid & 3;
            int gr = bm + r; if (gr > MQ - 1) gr = MQ - 1;
            u16x8 v = *(const u16x8*)(Ag + (size_t)gr * 256 + k0 + s * 8);
            *(u16x8*)&Ah[r * 40 + s * 8] = v;
            if (split) {
                u16x8 vl = *(const u16x8*)(Ql + (size_t)gr * 256 + k0 + s * 8);
                *(u16x8*)&Al[r * 40 + s * 8] = vl;
            }
            int gn = bn + r; if (gn > N - 1) gn = N - 1;
            u16x8 bv = *(const u16x8*)(Bg + (size_t)gn * 256 + k0 + s * 8);
            *(u16x8*)&Bs[r * 40 + s * 8] = bv;
            if (split) {
                u16x8 bl = *(const u16x8*)(Wcl + (size_t)gn * 256 + k0 + s * 8);
                *(u16x8*)&Bl2[r * 40 + s * 8] = bl;
            }
        }
        __syncthreads();

        s16x8 af[4], bfv[4];
        #pragma unroll
        for (int mt = 0; mt < 4; ++mt)
            af[mt] = *(const s16x8*)&Ah[(wm + mt * 16 + l15) * 40 + quad * 8];
        #pragma unroll
        for (int nt = 0; nt < 4; ++nt)
            bfv[nt] = *(const s16x8*)&Bs[(wn + nt * 16 + l15) * 40 + quad * 8];

        if (split) {
            s16x8 alf[4], blf[4];
            #pragma unroll
            for (int mt = 0; mt < 4; ++mt)
                alf[mt] = *(const s16x8*)&Al[(wm + mt * 16 + l15) * 40 + quad * 8];
            #pragma unroll
            for (int nt = 0; nt < 4; ++nt)
                blf[nt] = *(const s16x8*)&Bl2[(wn + nt * 16 + l15) * 40 + quad * 8];
            #pragma unroll
            for (int mt = 0; mt < 4; ++mt)
                #pragma unroll
                for (int nt = 0; nt < 4; ++nt) {
                    acc[mt][nt] = __builtin_amdgcn_mfma_f32_16x16x32_bf16(af[mt], bfv[nt], acc[mt][nt], 0, 0, 0);
                    acc[mt][nt] = __builtin_amdgcn_mfma_f32_16x16x32_bf16(af[mt], blf[nt], acc[mt][nt], 0, 0, 0);
                    acc[mt][nt] = __builtin_amdgcn_mfma_f32_16x16x32_bf16(alf[mt], bfv[nt], acc[mt][nt], 0, 0, 0);
                }
        } else {
            #pragma unroll
            for (int mt = 0; mt < 4; ++mt)
                #pragma unroll
                for (int nt = 0; nt < 4; ++nt)
                    acc[mt][nt] = __builtin_amdgcn_mfma_f32_16x16x32_bf16(af[mt], bfv[nt], acc[mt][nt], 0, 0, 0);
        }
        __syncthreads();
    }

    #pragma unroll
    for (int nt = 0; nt < 4; ++nt) {
        int col = bn + wn + nt * 16 + l15;
        float bv = (col < N) ? (split ? bcat[col] : b_val[col]) : 0.f;
        #pragma unroll
        for (int mt = 0; mt < 4; ++mt) {
            int row0 = bm + wm + mt * 16 + quad * 4;
            #pragma unroll
            for (int r = 0; r < 4; ++r) {
                int row = row0 + r;
                if (row < MQ && col < N) {
                    float v = acc[mt][nt][r] + bv;
                    if (!split) {
                        int bb = row / STOT, s = row - bb * STOT;
                        int h = col >> 5, c = col & 31;
                        valb[(((size_t)(bb * 8 + h)) * STOT + s) * 32 + c] = f2bf(v);
                    } else if (col < 192) {
                        raw_off[(size_t)row * 192 + col] = v;
                    } else {
                        attnb[(size_t)row * 96 + (col - 192)] = f2bf(v);
                    }
                }
            }
        }
    }
}

// ---------------------------------------------------------------------------
// Plain GEMM for output projection: A bf16 [M][256] * Wot^T + b -> fp32.
__global__ __launch_bounds__(256) void gemm_o(
    const unsigned short* __restrict__ A, const unsigned short* __restrict__ Bt,
    const float* __restrict__ bias, float* __restrict__ C)
{
    __shared__ unsigned short Ah[128 * 40];
    __shared__ unsigned short Bs[128 * 40];
    const int t = threadIdx.x;
    const int bn = blockIdx.x * 128, bm = blockIdx.y * 128;
    const int lane = t & 63, w = t >> 6;
    const int wm = (w & 1) * 64, wn = (w >> 1) * 64;
    const int l15 = lane & 15, quad = lane >> 4;

    f32x4 acc[4][4];
    #pragma unroll
    for (int i = 0; i < 4; ++i)
        #pragma unroll
        for (int j = 0; j < 4; ++j)
            acc[i][j] = (f32x4){0.f, 0.f, 0.f, 0.f};

    for (int k0 = 0; k0 < 256; k0 += 32) {
        #pragma unroll
        for (int cc = 0; cc < 2; ++cc) {
            int cid = t + cc * 256;
            int r = cid >> 2, s = cid & 3;
            int gr = bm + r; if (gr > MQ - 1) gr = MQ - 1;
            *(u16x8*)&Ah[r * 40 + s * 8] = *(const u16x8*)(A + (size_t)gr * 256 + k0 + s * 8);
            *(u16x8*)&Bs[r * 40 + s * 8] = *(const u16x8*)(Bt + (size_t)(bn + r) * 256 + k0 + s * 8);
        }
        __syncthreads();
        s16x8 af[4], bfv[4];
        #pragma unroll
        for (int mt = 0; mt < 4; ++mt)
            af[mt] = *(const s16x8*)&Ah[(wm + mt * 16 + l15) * 40 + quad * 8];
        #pragma unroll
        for (int nt = 0; nt < 4; ++nt)
            bfv[nt] = *(const s16x8*)&Bs[(wn + nt * 16 + l15) * 40 + quad * 8];
        #pragma unroll
        for (int mt = 0; mt < 4; ++mt)
            #pragma unroll
            for (int nt = 0; nt < 4; ++nt)
                acc[mt][nt] = __builtin_amdgcn_mfma_f32_16x16x32_bf16(af[mt], bfv[nt], acc[mt][nt], 0, 0, 0);
        __syncthreads();
    }
    #pragma unroll
    for (int nt = 0; nt < 4; ++nt) {
        int col = bn + wn + nt * 16 + l15;
        float bv = bias[col];
        #pragma unroll
        for (int mt = 0; mt < 4; ++mt) {
            int row0 = bm + wm + mt * 16 + quad * 4;
            #pragma unroll
            for (int r = 0; r < 4; ++r) {
                int row = row0 + r;
                if (row < MQ)
                    C[(size_t)row * 256 + col] = acc[mt][nt][r] + bv;
            }
        }
    }
}

// ---------------------------------------------------------------------------
// Sampler: 8 q/block, XCD-swizzled so each batch's 4.3MB val table stays in
// one XCD-pair's L2.
__global__ __launch_bounds__(256) void sample_v4(
    const unsigned short* __restrict__ valb, // [B*8][STOT][32] bf16
    const float* __restrict__ raw_off,       // [MQ][192]
    const unsigned short* __restrict__ attnb,// [MQ][96] bf16
    const float* __restrict__ refp,          // [MQ][2]
    unsigned short* __restrict__ out_bf)     // [MQ][256] bf16
{
    const int bx = blockIdx.x;
    const int xcd = bx & 7;
    const int b = xcd >> 1;                       // batch -> XCD pair
    const int qi = (bx >> 3) * 2 + (xcd & 1);     // 0..1049
    const int bq0 = b * NQ + qi * 8;
    const int t = threadIdx.x;

    __shared__ int   s_idx[8][96][4];
    __shared__ float s_w[8][96][4];
    __shared__ float s_m[8][8];
    __shared__ float s_inv[8][8];

    if (t < 64) {
        int q = t >> 3, h = t & 7;
        const unsigned short* a = attnb + (size_t)(bq0 + q) * 96 + h * 12;
        float m = bf2f(a[0]);
        #pragma unroll
        for (int j = 1; j < 12; ++j) m = fmaxf(m, bf2f(a[j]));
        float s = 0.f;
        #pragma unroll
        for (int j = 0; j < 12; ++j) s += expf(bf2f(a[j]) - m);
        s_m[q][h] = m;
        s_inv[q][h] = 1.f / s;
    }
    __syncthreads();

    for (int i = t; i < 768; i += 256) {
        int q = i / 96, p = i - q * 96;
        int h = p / 12, lp = p - h * 12, l = lp >> 2;
        const int dims[3]   = {80, 40, 20};
        const int bases_[3] = {0, 6400, 8000};
        int Wl = dims[l], base = bases_[l];
        float logit = bf2f(attnb[(size_t)(bq0 + q) * 96 + p]);
        float aw = expf(logit - s_m[q][h]) * s_inv[q][h];
        size_t ro = (size_t)(bq0 + q) * 192 + h * 24 + lp * 2;
        float rawx = raw_off[ro], rawy = raw_off[ro + 1];
        float rx = refp[(size_t)(bq0 + q) * 2];
        float ry = refp[(size_t)(bq0 + q) * 2 + 1];
        float ix = (rx + tanhf(rawx) * 0.5f) * Wl - 0.5f;
        float iy = (ry + tanhf(rawy) * 0.5f) * Wl - 0.5f;
        float x0f = floorf(ix), y0f = floorf(iy);
        float fx = ix - x0f, fy = iy - y0f;
        int x0 = (int)x0f, y0 = (int)y0f;
        float w00 = (1.f - fx) * (1.f - fy) * aw;
        float w01 = fx * (1.f - fy) * aw;
        float w10 = (1.f - fx) * fy * aw;
        float w11 = fx * fy * aw;
        bool vx0 = (unsigned)x0 < (unsigned)Wl;
        bool vx1 = (unsigned)(x0 + 1) < (unsigned)Wl;
        bool vy0 = (unsigned)y0 < (unsigned)Wl;
        bool vy1 = (unsigned)(y0 + 1) < (unsigned)Wl;
        int row0 = base + y0 * Wl, row1 = row0 + Wl;
        s_idx[q][p][0] = (vx0 && vy0) ? row0 + x0     : 0;  s_w[q][p][0] = (vx0 && vy0) ? w00 : 0.f;
        s_idx[q][p][1] = (vx1 && vy0) ? row0 + x0 + 1 : 0;  s_w[q][p][1] = (vx1 && vy0) ? w01 : 0.f;
        s_idx[q][p][2] = (vx0 && vy1) ? row1 + x0     : 0;  s_w[q][p][2] = (vx0 && vy1) ? w10 : 0.f;
        s_idx[q][p][3] = (vx1 && vy1) ? row1 + x0 + 1 : 0;  s_w[q][p][3] = (vx1 && vy1) ? w11 : 0.f;
    }
    __syncthreads();

    const int q = t >> 5;
    const int h = (t >> 2) & 7;
    const int l4 = t & 3;
    const unsigned short* vb = valb + ((size_t)(b * 8 + h) * STOT) * 32 + l4 * 8;
    const int*   ip = &s_idx[q][h * 12][0];
    const float* wp = &s_w[q][h * 12][0];
    float acc[8] = {};
    #pragma unroll
    for (int pp = 0; pp < 4; ++pp) {
        int   ix[12]; float ww[12]; u16x8 v[12];
        #pragma unroll
        for (int k = 0; k < 12; ++k) { ix[k] = ip[pp * 12 + k]; ww[k] = wp[pp * 12 + k]; }
        #pragma unroll
        for (int k = 0; k < 12; ++k) v[k] = *(const u16x8*)(vb + (size_t)ix[k] * 32);
        #pragma unroll
        for (int k = 0; k < 12; ++k)
            #pragma unroll
            for (int c = 0; c < 8; ++c)
                acc[c] = fmaf(ww[k], bf2f(v[k][c]), acc[c]);
    }
    u16x8 ob;
    #pragma unroll
    for (int c = 0; c < 8; ++c) ob[c] = f2bf(acc[c]);
    *(u16x8*)&out_bf[(size_t)(bq0 + q) * 256 + h * 32 + l4 * 8] = ob;
}

// ---------------------------------------------------------------------------
extern "C" void kernel_launch(void* const* d_in, const int* in_sizes, int n_in,
                              void* d_out, int out_size, void* d_ws, size_t ws_size,
                              hipStream_t stream)
{
    const float* query  = (const float*)d_in[0];
    const float* feat0  = (const float*)d_in[1];
    const float* feat1  = (const float*)d_in[2];
    const float* feat2  = (const float*)d_in[3];
    const float* refp   = (const float*)d_in[4];
    const float* W_off  = (const float*)d_in[5];
    const float* b_off  = (const float*)d_in[6];
    const float* W_attn = (const float*)d_in[7];
    const float* b_attn = (const float*)d_in[8];
    const float* W_val  = (const float*)d_in[9];
    const float* b_val  = (const float*)d_in[10];
    const float* W_out  = (const float*)d_in[11];
    const float* b_out  = (const float*)d_in[12];
    float* out = (float*)d_out;

    // workspace (~101.6 MB)
    unsigned short* valb  = (unsigned short*)d_ws;            // MQ*256 bf16
    float*          rawo  = (float*)(valb + (size_t)MQ * 256);// MQ*192 f32
    unsigned short* attnb = (unsigned short*)(rawo + (size_t)MQ * 192); // MQ*96 bf16
    unsigned short* Abf   = attnb + (size_t)MQ * 96;          // MQ*256 bf16
    unsigned short* outb  = Abf;                              // reuse after gemm_vr
    unsigned short* Qh    = Abf + (size_t)MQ * 256;
    unsigned short* Ql    = Qh + (size_t)MQ * 256;
    unsigned short* Wvt   = Ql + (size_t)MQ * 256;            // 256*256
    unsigned short* Wot   = Wvt + 65536;
    unsigned short* Wch   = Wot + 65536;                      // 288*256
    unsigned short* Wcl   = Wch + 73728;
    float*          bcat  = (float*)(Wcl + 73728);

    dim3 blk(256);

    prep_w<<<dim3(8, 8, 5), blk, 0, stream>>>(W_val, W_out, W_off, W_attn,
                                              b_off, b_attn, Wvt, Wot, Wch, Wcl, bcat);
    prep_af<<<dim3(263, 8, 8), blk, 0, stream>>>(feat0, feat1, feat2, query, Abf, Qh, Ql);
    gemm_vr<<<dim3(5, 263), blk, 0, stream>>>(Abf, Qh, Ql, Wvt, Wch, Wcl,
                                              b_val, bcat, valb, rawo, attnb);
    sample_v4<<<dim3(MQ / 8), blk, 0, stream>>>(valb, rawo, attnb, refp, outb);
    gemm_o<<<dim3(2, 263), blk, 0, stream>>>(outb, Wot, b_out, out);
}

// Round 5
// 252.236 us; speedup vs baseline: 1.1372x; 1.1372x over previous
//
#include <hip/hip_runtime.h>
#include <math.h>

#define NH    8
#define DIM   256
#define NQ    8400
#define BATCH 4
#define STOT  8400
#define MQ    (BATCH * NQ)   // 33600

typedef _Float16 f16;
typedef __attribute__((ext_vector_type(8))) _Float16 f16x8;
typedef __attribute__((ext_vector_type(8))) unsigned short u16x8;
typedef __attribute__((ext_vector_type(4))) float  f32x4;

// ---------------------------------------------------------------------------
// Weight transposes (fp32 [K][Nw] -> fp16 [n][256]) + bias concat.
__global__ __launch_bounds__(256) void prep_w(
    const float* __restrict__ W_val, const float* __restrict__ W_out,
    const float* __restrict__ W_off, const float* __restrict__ W_attn,
    const float* __restrict__ b_off, const float* __restrict__ b_attn,
    f16* __restrict__ Wvt, f16* __restrict__ Wot, f16* __restrict__ Wch,
    float* __restrict__ bcat)
{
    const int z = blockIdx.z;
    const int t = threadIdx.x;
    if (z == 4) {
        if (blockIdx.x == 0 && blockIdx.y == 0)
            for (int i = t; i < 288; i += 256)
                bcat[i] = (i < 192) ? b_off[i] : b_attn[i - 192];
        return;
    }
    const float* W; f16* oH; int Nw, n0;
    switch (z) {
        case 0:  W = W_val;  oH = Wvt; Nw = 256; n0 = 0;   break;
        case 1:  W = W_out;  oH = Wot; Nw = 256; n0 = 0;   break;
        case 2:  W = W_off;  oH = Wch; Nw = 192; n0 = 0;   break;
        default: W = W_attn; oH = Wch; Nw = 96;  n0 = 192; break;
    }
    const int nb = blockIdx.x * 32, k0 = blockIdx.y * 32;
    if (nb >= Nw) return;
    __shared__ float tile[32][33];
    const int c = t & 31, r = t >> 5;
    #pragma unroll
    for (int i = 0; i < 4; ++i) {
        int k = k0 + r + i * 8, n = nb + c;
        tile[r + i * 8][c] = (n < Nw) ? W[(size_t)k * Nw + n] : 0.f;
    }
    __syncthreads();
    #pragma unroll
    for (int i = 0; i < 4; ++i) {
        int n = nb + r + i * 8, k = k0 + c;
        if (n < Nw)
            oH[(size_t)(n0 + n) * 256 + k] = (f16)tile[c][r + i * 8];
    }
}

// ---------------------------------------------------------------------------
// z=0..3: feat transpose (3 levels concat) for batch z -> Af[(b*8400+s)*256+k].
// z=4..7: query fp32 -> fp16 elementwise.
__global__ __launch_bounds__(256) void prep_af(
    const float* __restrict__ feat0, const float* __restrict__ feat1,
    const float* __restrict__ feat2, const float* __restrict__ query,
    f16* __restrict__ Af, f16* __restrict__ Qh)
{
    const int z = blockIdx.z;
    const int t = threadIdx.x;
    if (z >= 4) {
        int lid = (z - 4) * 263 * 8 + blockIdx.x * 8 + blockIdx.y;
        size_t idx = (size_t)lid * 1024 + t * 4;
        if (idx < (size_t)MQ * 256) {
            float4 q = *(const float4*)(query + idx);
            f16 h0 = (f16)q.x, h1 = (f16)q.y, h2 = (f16)q.z, h3 = (f16)q.w;
            ushort4 hv;
            hv.x = __builtin_bit_cast(unsigned short, h0);
            hv.y = __builtin_bit_cast(unsigned short, h1);
            hv.z = __builtin_bit_cast(unsigned short, h2);
            hv.w = __builtin_bit_cast(unsigned short, h3);
            *(ushort4*)((unsigned short*)Qh + idx) = hv;
        }
        return;
    }
    const int b = z;
    const int s0 = blockIdx.x * 32, k0 = blockIdx.y * 32;
    const float* f0b = feat0 + (size_t)b * 256 * 6400;
    const float* f1b = feat1 + (size_t)b * 256 * 1600;
    const float* f2b = feat2 + (size_t)b * 256 * 400;
    __shared__ float tile[32][33];
    const int c = t & 31, r = t >> 5;
    #pragma unroll
    for (int i = 0; i < 4; ++i) {
        int rr = r + i * 8;
        int s = s0 + c;
        float v = 0.f;
        if (s < 8400) {
            const float* fp; int S, sl;
            if (s < 6400)      { fp = f0b; S = 6400; sl = s; }
            else if (s < 8000) { fp = f1b; S = 1600; sl = s - 6400; }
            else               { fp = f2b; S = 400;  sl = s - 8000; }
            v = fp[(size_t)(k0 + rr) * S + sl];
        }
        tile[rr][c] = v;
    }
    __syncthreads();
    #pragma unroll
    for (int i = 0; i < 4; ++i) {
        int s = s0 + r + i * 8, k = k0 + c;
        if (s < 8400)
            Af[((size_t)b * 8400 + s) * 256 + k] = (f16)tile[c][r + i * 8];
    }
}

// ---------------------------------------------------------------------------
// Fused val-projection + offset/attn GEMM, all fp16 single-pass.
// blockIdx.x<2: val (A=Af, B=Wvt, N=256, fp16 head-plane epilogue).
// blockIdx.x>=2: raw (A=Qh, B=Wch, N=288; cols<192 -> fp32 rawo, else fp16 attnh).
// 128x128 tile, BK=32, mfma_f32_16x16x32_f16.
__global__ __launch_bounds__(256) void gemm_vr(
    const f16* __restrict__ Af, const f16* __restrict__ Qh,
    const f16* __restrict__ Wvt, const f16* __restrict__ Wch,
    const float* __restrict__ b_val, const float* __restrict__ bcat,
    f16* __restrict__ valh, float* __restrict__ rawo, f16* __restrict__ attnh)
{
    __shared__ unsigned short Ah[128 * 40];
    __shared__ unsigned short Bs[128 * 40];

    const bool split = blockIdx.x >= 2;
    const int bn = split ? (blockIdx.x - 2) * 128 : blockIdx.x * 128;
    const int bm = blockIdx.y * 128;
    const int N = split ? 288 : 256;
    const unsigned short* Ag = (const unsigned short*)(split ? Qh : Af);
    const unsigned short* Bg = (const unsigned short*)(split ? Wch : Wvt);

    const int t = threadIdx.x;
    const int lane = t & 63, w = t >> 6;
    const int wm = (w & 1) * 64, wn = (w >> 1) * 64;
    const int l15 = lane & 15, quad = lane >> 4;

    f32x4 acc[4][4];
    #pragma unroll
    for (int i = 0; i < 4; ++i)
        #pragma unroll
        for (int j = 0; j < 4; ++j)
            acc[i][j] = (f32x4){0.f, 0.f, 0.f, 0.f};

    for (int k0 = 0; k0 < 256; k0 += 32) {
        #pragma unroll
        for (int cc = 0; cc < 2; ++cc) {
            int cid = t + cc * 256;
            int r = cid >> 2, s = cid & 3;
            int gr = bm + r; if (gr > MQ - 1) gr = MQ - 1;
            *(u16x8*)&Ah[r * 40 + s * 8] = *(const u16x8*)(Ag + (size_t)gr * 256 + k0 + s * 8);
            int gn = bn + r; if (gn > N - 1) gn = N - 1;
            *(u16x8*)&Bs[r * 40 + s * 8] = *(const u16x8*)(Bg + (size_t)gn * 256 + k0 + s * 8);
        }
        __syncthreads();

        f16x8 af[4], bfv[4];
        #pragma unroll
        for (int mt = 0; mt < 4; ++mt)
            af[mt] = *(const f16x8*)&Ah[(wm + mt * 16 + l15) * 40 + quad * 8];
        #pragma unroll
        for (int nt = 0; nt < 4; ++nt)
            bfv[nt] = *(const f16x8*)&Bs[(wn + nt * 16 + l15) * 40 + quad * 8];
        #pragma unroll
        for (int mt = 0; mt < 4; ++mt)
            #pragma unroll
            for (int nt = 0; nt < 4; ++nt)
                acc[mt][nt] = __builtin_amdgcn_mfma_f32_16x16x32_f16(af[mt], bfv[nt], acc[mt][nt], 0, 0, 0);
        __syncthreads();
    }

    #pragma unroll
    for (int nt = 0; nt < 4; ++nt) {
        int col = bn + wn + nt * 16 + l15;
        float bv = (col < N) ? (split ? bcat[col] : b_val[col]) : 0.f;
        #pragma unroll
        for (int mt = 0; mt < 4; ++mt) {
            int row0 = bm + wm + mt * 16 + quad * 4;
            #pragma unroll
            for (int r = 0; r < 4; ++r) {
                int row = row0 + r;
                if (row < MQ && col < N) {
                    float v = acc[mt][nt][r] + bv;
                    if (!split) {
                        int bb = row / STOT, s = row - bb * STOT;
                        int h = col >> 5, c = col & 31;
                        valh[(((size_t)(bb * 8 + h)) * STOT + s) * 32 + c] = (f16)v;
                    } else if (col < 192) {
                        rawo[(size_t)row * 192 + col] = v;
                    } else {
                        attnh[(size_t)row * 96 + (col - 192)] = (f16)v;
                    }
                }
            }
        }
    }
}

// ---------------------------------------------------------------------------
// Output projection: A fp16 [M][256] * Wot^T + b -> fp32.
__global__ __launch_bounds__(256) void gemm_o(
    const f16* __restrict__ A, const f16* __restrict__ Bt,
    const float* __restrict__ bias, float* __restrict__ C)
{
    __shared__ unsigned short Ah[128 * 40];
    __shared__ unsigned short Bs[128 * 40];
    const int t = threadIdx.x;
    const int bn = blockIdx.x * 128, bm = blockIdx.y * 128;
    const int lane = t & 63, w = t >> 6;
    const int wm = (w & 1) * 64, wn = (w >> 1) * 64;
    const int l15 = lane & 15, quad = lane >> 4;

    f32x4 acc[4][4];
    #pragma unroll
    for (int i = 0; i < 4; ++i)
        #pragma unroll
        for (int j = 0; j < 4; ++j)
            acc[i][j] = (f32x4){0.f, 0.f, 0.f, 0.f};

    for (int k0 = 0; k0 < 256; k0 += 32) {
        #pragma unroll
        for (int cc = 0; cc < 2; ++cc) {
            int cid = t + cc * 256;
            int r = cid >> 2, s = cid & 3;
            int gr = bm + r; if (gr > MQ - 1) gr = MQ - 1;
            *(u16x8*)&Ah[r * 40 + s * 8] = *(const u16x8*)((const unsigned short*)A + (size_t)gr * 256 + k0 + s * 8);
            *(u16x8*)&Bs[r * 40 + s * 8] = *(const u16x8*)((const unsigned short*)Bt + (size_t)(bn + r) * 256 + k0 + s * 8);
        }
        __syncthreads();
        f16x8 af[4], bfv[4];
        #pragma unroll
        for (int mt = 0; mt < 4; ++mt)
            af[mt] = *(const f16x8*)&Ah[(wm + mt * 16 + l15) * 40 + quad * 8];
        #pragma unroll
        for (int nt = 0; nt < 4; ++nt)
            bfv[nt] = *(const f16x8*)&Bs[(wn + nt * 16 + l15) * 40 + quad * 8];
        #pragma unroll
        for (int mt = 0; mt < 4; ++mt)
            #pragma unroll
            for (int nt = 0; nt < 4; ++nt)
                acc[mt][nt] = __builtin_amdgcn_mfma_f32_16x16x32_f16(af[mt], bfv[nt], acc[mt][nt], 0, 0, 0);
        __syncthreads();
    }
    #pragma unroll
    for (int nt = 0; nt < 4; ++nt) {
        int col = bn + wn + nt * 16 + l15;
        float bv = bias[col];
        #pragma unroll
        for (int mt = 0; mt < 4; ++mt) {
            int row0 = bm + wm + mt * 16 + quad * 4;
            #pragma unroll
            for (int r = 0; r < 4; ++r) {
                int row = row0 + r;
                if (row < MQ)
                    C[(size_t)row * 256 + col] = acc[mt][nt][r] + bv;
            }
        }
    }
}

// ---------------------------------------------------------------------------
// Sampler: 8 q/block, fp16 val head planes, XCD-swizzled for L2 locality.
__global__ __launch_bounds__(256) void sample_v5(
    const f16* __restrict__ valh,        // [B*8][STOT][32] fp16
    const float* __restrict__ raw_off,   // [MQ][192]
    const f16* __restrict__ attnh,       // [MQ][96] fp16
    const float* __restrict__ refp,      // [MQ][2]
    f16* __restrict__ out_h)             // [MQ][256] fp16
{
    const int bx = blockIdx.x;
    const int xcd = bx & 7;
    const int b = xcd >> 1;
    const int qi = (bx >> 3) * 2 + (xcd & 1);
    const int bq0 = b * NQ + qi * 8;
    const int t = threadIdx.x;

    __shared__ int   s_idx[8][96][4];
    __shared__ float s_w[8][96][4];
    __shared__ float s_m[8][8];
    __shared__ float s_inv[8][8];

    if (t < 64) {
        int q = t >> 3, h = t & 7;
        const f16* a = attnh + (size_t)(bq0 + q) * 96 + h * 12;
        float m = (float)a[0];
        #pragma unroll
        for (int j = 1; j < 12; ++j) m = fmaxf(m, (float)a[j]);
        float s = 0.f;
        #pragma unroll
        for (int j = 0; j < 12; ++j) s += expf((float)a[j] - m);
        s_m[q][h] = m;
        s_inv[q][h] = 1.f / s;
    }
    __syncthreads();

    for (int i = t; i < 768; i += 256) {
        int q = i / 96, p = i - q * 96;
        int h = p / 12, lp = p - h * 12, l = lp >> 2;
        const int dims[3]   = {80, 40, 20};
        const int bases_[3] = {0, 6400, 8000};
        int Wl = dims[l], base = bases_[l];
        float logit = (float)attnh[(size_t)(bq0 + q) * 96 + p];
        float aw = expf(logit - s_m[q][h]) * s_inv[q][h];
        size_t ro = (size_t)(bq0 + q) * 192 + h * 24 + lp * 2;
        float rawx = raw_off[ro], rawy = raw_off[ro + 1];
        float rx = refp[(size_t)(bq0 + q) * 2];
        float ry = refp[(size_t)(bq0 + q) * 2 + 1];
        float ix = (rx + tanhf(rawx) * 0.5f) * Wl - 0.5f;
        float iy = (ry + tanhf(rawy) * 0.5f) * Wl - 0.5f;
        float x0f = floorf(ix), y0f = floorf(iy);
        float fx = ix - x0f, fy = iy - y0f;
        int x0 = (int)x0f, y0 = (int)y0f;
        float w00 = (1.f - fx) * (1.f - fy) * aw;
        float w01 = fx * (1.f - fy) * aw;
        float w10 = (1.f - fx) * fy * aw;
        float w11 = fx * fy * aw;
        bool vx0 = (unsigned)x0 < (unsigned)Wl;
        bool vx1 = (unsigned)(x0 + 1) < (unsigned)Wl;
        bool vy0 = (unsigned)y0 < (unsigned)Wl;
        bool vy1 = (unsigned)(y0 + 1) < (unsigned)Wl;
        int row0 = base + y0 * Wl, row1 = row0 + Wl;
        s_idx[q][p][0] = (vx0 && vy0) ? row0 + x0     : 0;  s_w[q][p][0] = (vx0 && vy0) ? w00 : 0.f;
        s_idx[q][p][1] = (vx1 && vy0) ? row0 + x0 + 1 : 0;  s_w[q][p][1] = (vx1 && vy0) ? w01 : 0.f;
        s_idx[q][p][2] = (vx0 && vy1) ? row1 + x0     : 0;  s_w[q][p][2] = (vx0 && vy1) ? w10 : 0.f;
        s_idx[q][p][3] = (vx1 && vy1) ? row1 + x0 + 1 : 0;  s_w[q][p][3] = (vx1 && vy1) ? w11 : 0.f;
    }
    __syncthreads();

    const int q = t >> 5;
    const int h = (t >> 2) & 7;
    const int l4 = t & 3;
    const f16* vb = valh + ((size_t)(b * 8 + h) * STOT) * 32 + l4 * 8;
    const int*   ip = &s_idx[q][h * 12][0];
    const float* wp = &s_w[q][h * 12][0];
    float acc[8] = {};
    #pragma unroll
    for (int pp = 0; pp < 4; ++pp) {
        int   ix[12]; float ww[12]; f16x8 v[12];
        #pragma unroll
        for (int k = 0; k < 12; ++k) { ix[k] = ip[pp * 12 + k]; ww[k] = wp[pp * 12 + k]; }
        #pragma unroll
        for (int k = 0; k < 12; ++k) v[k] = *(const f16x8*)(vb + (size_t)ix[k] * 32);
        #pragma unroll
        for (int k = 0; k < 12; ++k)
            #pragma unroll
            for (int c = 0; c < 8; ++c)
                acc[c] = fmaf(ww[k], (float)v[k][c], acc[c]);
    }
    f16x8 ob;
    #pragma unroll
    for (int c = 0; c < 8; ++c) ob[c] = (f16)acc[c];
    *(f16x8*)(out_h + (size_t)(bq0 + q) * 256 + h * 32 + l4 * 8) = ob;
}

// ---------------------------------------------------------------------------
extern "C" void kernel_launch(void* const* d_in, const int* in_sizes, int n_in,
                              void* d_out, int out_size, void* d_ws, size_t ws_size,
                              hipStream_t stream)
{
    const float* query  = (const float*)d_in[0];
    const float* feat0  = (const float*)d_in[1];
    const float* feat1  = (const float*)d_in[2];
    const float* feat2  = (const float*)d_in[3];
    const float* refp   = (const float*)d_in[4];
    const float* W_off  = (const float*)d_in[5];
    const float* b_off  = (const float*)d_in[6];
    const float* W_attn = (const float*)d_in[7];
    const float* b_attn = (const float*)d_in[8];
    const float* W_val  = (const float*)d_in[9];
    const float* b_val  = (const float*)d_in[10];
    const float* W_out  = (const float*)d_in[11];
    const float* b_out  = (const float*)d_in[12];
    float* out = (float*)d_out;

    // workspace (~84 MB)
    f16*   valh  = (f16*)d_ws;                               // MQ*256 fp16
    float* rawo  = (float*)(valh + (size_t)MQ * 256);        // MQ*192 f32
    f16*   attnh = (f16*)(rawo + (size_t)MQ * 192);          // MQ*96 fp16
    f16*   Af    = attnh + (size_t)MQ * 96;                  // MQ*256 fp16
    f16*   outh  = Af;                                       // reuse after gemm_vr
    f16*   Qh    = Af + (size_t)MQ * 256;                    // MQ*256 fp16
    f16*   Wvt   = Qh + (size_t)MQ * 256;                    // 256*256
    f16*   Wot   = Wvt + 65536;
    f16*   Wch   = Wot + 65536;                              // 288*256
    float* bcat  = (float*)(Wch + 73728);

    dim3 blk(256);

    prep_w<<<dim3(8, 8, 5), blk, 0, stream>>>(W_val, W_out, W_off, W_attn,
                                              b_off, b_attn, Wvt, Wot, Wch, bcat);
    prep_af<<<dim3(263, 8, 8), blk, 0, stream>>>(feat0, feat1, feat2, query, Af, Qh);
    gemm_vr<<<dim3(5, 263), blk, 0, stream>>>(Af, Qh, Wvt, Wch, b_val, bcat,
                                              valh, rawo, attnh);
    sample_v5<<<dim3(MQ / 8), blk, 0, stream>>>(valh, rawo, attnh, refp, outh);
    gemm_o<<<dim3(2, 263), blk, 0, stream>>>(outh, Wot, b_out, out);
}

// Round 6
// 251.300 us; speedup vs baseline: 1.1414x; 1.0037x over previous
//
#include <hip/hip_runtime.h>
#include <math.h>

#define NH    8
#define DIM   256
#define NQ    8400
#define BATCH 4
#define STOT  8400
#define MQ    (BATCH * NQ)   // 33600

typedef _Float16 f16;
typedef __attribute__((ext_vector_type(2))) _Float16 f16x2;
typedef __attribute__((ext_vector_type(8))) _Float16 f16x8;
typedef __attribute__((ext_vector_type(8))) unsigned short u16x8;
typedef __attribute__((ext_vector_type(4))) float  f32x4;

// ---------------------------------------------------------------------------
// Fused prep: z=0..3 feat transpose (3 levels concat) for batch z;
// z=4: weight transposes (fp32 [K][Nw] -> fp16 [n][256]) + bias concat.
__global__ __launch_bounds__(256) void prep_all(
    const float* __restrict__ feat0, const float* __restrict__ feat1,
    const float* __restrict__ feat2,
    const float* __restrict__ W_val, const float* __restrict__ W_out,
    const float* __restrict__ W_off, const float* __restrict__ W_attn,
    const float* __restrict__ b_off, const float* __restrict__ b_attn,
    f16* __restrict__ Af, f16* __restrict__ Wvt, f16* __restrict__ Wot,
    f16* __restrict__ Wch, float* __restrict__ bcat)
{
    const int z = blockIdx.z;
    const int t = threadIdx.x;
    __shared__ float tile[32][33];
    const int c = t & 31, r = t >> 5;

    if (z == 4) {
        const int xb = blockIdx.x;
        if (xb > 25) return;
        if (xb == 25) {
            if (blockIdx.y == 0)
                for (int i = t; i < 288; i += 256)
                    bcat[i] = (i < 192) ? b_off[i] : b_attn[i - 192];
            return;
        }
        const float* W; f16* oH; int Nw, n0, nb;
        if (xb < 8)       { W = W_val;  oH = Wvt; Nw = 256; n0 = 0;   nb = xb * 32; }
        else if (xb < 16) { W = W_out;  oH = Wot; Nw = 256; n0 = 0;   nb = (xb - 8) * 32; }
        else if (xb < 22) { W = W_off;  oH = Wch; Nw = 192; n0 = 0;   nb = (xb - 16) * 32; }
        else              { W = W_attn; oH = Wch; Nw = 96;  n0 = 192; nb = (xb - 22) * 32; }
        const int k0 = blockIdx.y * 32;
        #pragma unroll
        for (int i = 0; i < 4; ++i) {
            int k = k0 + r + i * 8, n = nb + c;
            tile[r + i * 8][c] = (n < Nw) ? W[(size_t)k * Nw + n] : 0.f;
        }
        __syncthreads();
        #pragma unroll
        for (int i = 0; i < 4; ++i) {
            int n = nb + r + i * 8, k = k0 + c;
            if (n < Nw)
                oH[(size_t)(n0 + n) * 256 + k] = (f16)tile[c][r + i * 8];
        }
        return;
    }

    const int b = z;
    const int s0 = blockIdx.x * 32, k0 = blockIdx.y * 32;
    if (s0 >= 8400) return;
    const float* f0b = feat0 + (size_t)b * 256 * 6400;
    const float* f1b = feat1 + (size_t)b * 256 * 1600;
    const float* f2b = feat2 + (size_t)b * 256 * 400;
    #pragma unroll
    for (int i = 0; i < 4; ++i) {
        int rr = r + i * 8;
        int s = s0 + c;
        float v = 0.f;
        if (s < 8400) {
            const float* fp; int S, sl;
            if (s < 6400)      { fp = f0b; S = 6400; sl = s; }
            else if (s < 8000) { fp = f1b; S = 1600; sl = s - 6400; }
            else               { fp = f2b; S = 400;  sl = s - 8000; }
            v = fp[(size_t)(k0 + rr) * S + sl];
        }
        tile[rr][c] = v;
    }
    __syncthreads();
    #pragma unroll
    for (int i = 0; i < 4; ++i) {
        int s = s0 + r + i * 8, k = k0 + c;
        if (s < 8400)
            Af[((size_t)b * 8400 + s) * 256 + k] = (f16)tile[c][r + i * 8];
    }
}

// ---------------------------------------------------------------------------
// Fused val-projection + offset/attn GEMM, fp16 MFMA, single pass.
// blockIdx.x<2: val (A=Af fp16, B=Wvt, N=256, fp16 head-plane epilogue).
// blockIdx.x>=2: raw (A=query fp32 converted in staging, B=Wch, N=288;
//                cols<192 -> fp32 rawo, else fp16 attnh).
__global__ __launch_bounds__(256) void gemm_vr(
    const f16* __restrict__ Af, const float* __restrict__ query,
    const f16* __restrict__ Wvt, const f16* __restrict__ Wch,
    const float* __restrict__ b_val, const float* __restrict__ bcat,
    f16* __restrict__ valh, float* __restrict__ rawo, f16* __restrict__ attnh)
{
    __shared__ unsigned short Ah[128 * 40];
    __shared__ unsigned short Bs[128 * 40];

    const bool split = blockIdx.x >= 2;
    const int bn = split ? (blockIdx.x - 2) * 128 : blockIdx.x * 128;
    const int bm = blockIdx.y * 128;
    const int N = split ? 288 : 256;
    const unsigned short* Bg = (const unsigned short*)(split ? Wch : Wvt);

    const int t = threadIdx.x;
    const int lane = t & 63, w = t >> 6;
    const int wm = (w & 1) * 64, wn = (w >> 1) * 64;
    const int l15 = lane & 15, quad = lane >> 4;

    f32x4 acc[4][4];
    #pragma unroll
    for (int i = 0; i < 4; ++i)
        #pragma unroll
        for (int j = 0; j < 4; ++j)
            acc[i][j] = (f32x4){0.f, 0.f, 0.f, 0.f};

    for (int k0 = 0; k0 < 256; k0 += 32) {
        #pragma unroll
        for (int cc = 0; cc < 2; ++cc) {
            int cid = t + cc * 256;
            int r = cid >> 2, s = cid & 3;
            int gr = bm + r; if (gr > MQ - 1) gr = MQ - 1;
            if (split) {
                const float* ap = query + (size_t)gr * 256 + k0 + s * 8;
                float4 q0 = *(const float4*)ap;
                float4 q1 = *(const float4*)(ap + 4);
                f16x8 hv;
                hv[0] = (f16)q0.x; hv[1] = (f16)q0.y; hv[2] = (f16)q0.z; hv[3] = (f16)q0.w;
                hv[4] = (f16)q1.x; hv[5] = (f16)q1.y; hv[6] = (f16)q1.z; hv[7] = (f16)q1.w;
                *(f16x8*)&Ah[r * 40 + s * 8] = hv;
            } else {
                *(u16x8*)&Ah[r * 40 + s * 8] =
                    *(const u16x8*)((const unsigned short*)Af + (size_t)gr * 256 + k0 + s * 8);
            }
            int gn = bn + r; if (gn > N - 1) gn = N - 1;
            *(u16x8*)&Bs[r * 40 + s * 8] = *(const u16x8*)(Bg + (size_t)gn * 256 + k0 + s * 8);
        }
        __syncthreads();

        f16x8 af[4], bfv[4];
        #pragma unroll
        for (int mt = 0; mt < 4; ++mt)
            af[mt] = *(const f16x8*)&Ah[(wm + mt * 16 + l15) * 40 + quad * 8];
        #pragma unroll
        for (int nt = 0; nt < 4; ++nt)
            bfv[nt] = *(const f16x8*)&Bs[(wn + nt * 16 + l15) * 40 + quad * 8];
        #pragma unroll
        for (int mt = 0; mt < 4; ++mt)
            #pragma unroll
            for (int nt = 0; nt < 4; ++nt)
                acc[mt][nt] = __builtin_amdgcn_mfma_f32_16x16x32_f16(af[mt], bfv[nt], acc[mt][nt], 0, 0, 0);
        __syncthreads();
    }

    #pragma unroll
    for (int nt = 0; nt < 4; ++nt) {
        int col = bn + wn + nt * 16 + l15;
        float bv = (col < N) ? (split ? bcat[col] : b_val[col]) : 0.f;
        #pragma unroll
        for (int mt = 0; mt < 4; ++mt) {
            int row0 = bm + wm + mt * 16 + quad * 4;
            #pragma unroll
            for (int r = 0; r < 4; ++r) {
                int row = row0 + r;
                if (row < MQ && col < N) {
                    float v = acc[mt][nt][r] + bv;
                    if (!split) {
                        int bb = row / STOT, s = row - bb * STOT;
                        int h = col >> 5, c = col & 31;
                        valh[(((size_t)(bb * 8 + h)) * STOT + s) * 32 + c] = (f16)v;
                    } else if (col < 192) {
                        rawo[(size_t)row * 192 + col] = v;
                    } else {
                        attnh[(size_t)row * 96 + (col - 192)] = (f16)v;
                    }
                }
            }
        }
    }
}

// ---------------------------------------------------------------------------
// Output projection: A fp16 [M][256] * Wot^T + b -> fp32.
__global__ __launch_bounds__(256) void gemm_o(
    const f16* __restrict__ A, const f16* __restrict__ Bt,
    const float* __restrict__ bias, float* __restrict__ C)
{
    __shared__ unsigned short Ah[128 * 40];
    __shared__ unsigned short Bs[128 * 40];
    const int t = threadIdx.x;
    const int bn = blockIdx.x * 128, bm = blockIdx.y * 128;
    const int lane = t & 63, w = t >> 6;
    const int wm = (w & 1) * 64, wn = (w >> 1) * 64;
    const int l15 = lane & 15, quad = lane >> 4;

    f32x4 acc[4][4];
    #pragma unroll
    for (int i = 0; i < 4; ++i)
        #pragma unroll
        for (int j = 0; j < 4; ++j)
            acc[i][j] = (f32x4){0.f, 0.f, 0.f, 0.f};

    for (int k0 = 0; k0 < 256; k0 += 32) {
        #pragma unroll
        for (int cc = 0; cc < 2; ++cc) {
            int cid = t + cc * 256;
            int r = cid >> 2, s = cid & 3;
            int gr = bm + r; if (gr > MQ - 1) gr = MQ - 1;
            *(u16x8*)&Ah[r * 40 + s * 8] = *(const u16x8*)((const unsigned short*)A + (size_t)gr * 256 + k0 + s * 8);
            *(u16x8*)&Bs[r * 40 + s * 8] = *(const u16x8*)((const unsigned short*)Bt + (size_t)(bn + r) * 256 + k0 + s * 8);
        }
        __syncthreads();
        f16x8 af[4], bfv[4];
        #pragma unroll
        for (int mt = 0; mt < 4; ++mt)
            af[mt] = *(const f16x8*)&Ah[(wm + mt * 16 + l15) * 40 + quad * 8];
        #pragma unroll
        for (int nt = 0; nt < 4; ++nt)
            bfv[nt] = *(const f16x8*)&Bs[(wn + nt * 16 + l15) * 40 + quad * 8];
        #pragma unroll
        for (int mt = 0; mt < 4; ++mt)
            #pragma unroll
            for (int nt = 0; nt < 4; ++nt)
                acc[mt][nt] = __builtin_amdgcn_mfma_f32_16x16x32_f16(af[mt], bfv[nt], acc[mt][nt], 0, 0, 0);
        __syncthreads();
    }
    #pragma unroll
    for (int nt = 0; nt < 4; ++nt) {
        int col = bn + wn + nt * 16 + l15;
        float bv = bias[col];
        #pragma unroll
        for (int mt = 0; mt < 4; ++mt) {
            int row0 = bm + wm + mt * 16 + quad * 4;
            #pragma unroll
            for (int r = 0; r < 4; ++r) {
                int row = row0 + r;
                if (row < MQ)
                    C[(size_t)row * 256 + col] = acc[mt][nt][r] + bv;
            }
        }
    }
}

// ---------------------------------------------------------------------------
// Sampler v6: packed-fp16 inner loop (v_pk_fma_f16), weights pre-packed (w,w),
// fp16 accumulators flushed to fp32 every 12 corners. XCD-swizzled.
__global__ __launch_bounds__(256) void sample_v6(
    const f16* __restrict__ valh,        // [B*8][STOT][32] fp16
    const float* __restrict__ raw_off,   // [MQ][192]
    const f16* __restrict__ attnh,       // [MQ][96] fp16
    const float* __restrict__ refp,      // [MQ][2]
    f16* __restrict__ out_h)             // [MQ][256] fp16
{
    const int bx = blockIdx.x;
    const int xcd = bx & 7;
    const int b = xcd >> 1;
    const int qi = (bx >> 3) * 2 + (xcd & 1);
    const int bq0 = b * NQ + qi * 8;
    const int t = threadIdx.x;

    __shared__ int      s_idx[8][96][4];
    __shared__ unsigned s_wp[8][96][4];   // packed (w,w) f16x2
    __shared__ float    s_m[8][8];
    __shared__ float    s_inv[8][8];

    if (t < 64) {
        int q = t >> 3, h = t & 7;
        const f16* a = attnh + (size_t)(bq0 + q) * 96 + h * 12;
        float m = (float)a[0];
        #pragma unroll
        for (int j = 1; j < 12; ++j) m = fmaxf(m, (float)a[j]);
        float s = 0.f;
        #pragma unroll
        for (int j = 0; j < 12; ++j) s += expf((float)a[j] - m);
        s_m[q][h] = m;
        s_inv[q][h] = 1.f / s;
    }
    __syncthreads();

    for (int i = t; i < 768; i += 256) {
        int q = i / 96, p = i - q * 96;
        int h = p / 12, lp = p - h * 12, l = lp >> 2;
        const int dims[3]   = {80, 40, 20};
        const int bases_[3] = {0, 6400, 8000};
        int Wl = dims[l], base = bases_[l];
        float logit = (float)attnh[(size_t)(bq0 + q) * 96 + p];
        float aw = expf(logit - s_m[q][h]) * s_inv[q][h];
        size_t ro = (size_t)(bq0 + q) * 192 + h * 24 + lp * 2;
        float rawx = raw_off[ro], rawy = raw_off[ro + 1];
        float rx = refp[(size_t)(bq0 + q) * 2];
        float ry = refp[(size_t)(bq0 + q) * 2 + 1];
        float ix = (rx + tanhf(rawx) * 0.5f) * Wl - 0.5f;
        float iy = (ry + tanhf(rawy) * 0.5f) * Wl - 0.5f;
        float x0f = floorf(ix), y0f = floorf(iy);
        float fx = ix - x0f, fy = iy - y0f;
        int x0 = (int)x0f, y0 = (int)y0f;
        float w00 = (1.f - fx) * (1.f - fy) * aw;
        float w01 = fx * (1.f - fy) * aw;
        float w10 = (1.f - fx) * fy * aw;
        float w11 = fx * fy * aw;
        bool vx0 = (unsigned)x0 < (unsigned)Wl;
        bool vx1 = (unsigned)(x0 + 1) < (unsigned)Wl;
        bool vy0 = (unsigned)y0 < (unsigned)Wl;
        bool vy1 = (unsigned)(y0 + 1) < (unsigned)Wl;
        int row0 = base + y0 * Wl, row1 = row0 + Wl;
        float ws[4] = { vx0 && vy0 ? w00 : 0.f, vx1 && vy0 ? w01 : 0.f,
                        vx0 && vy1 ? w10 : 0.f, vx1 && vy1 ? w11 : 0.f };
        int   is[4] = { vx0 && vy0 ? row0 + x0 : 0, vx1 && vy0 ? row0 + x0 + 1 : 0,
                        vx0 && vy1 ? row1 + x0 : 0, vx1 && vy1 ? row1 + x0 + 1 : 0 };
        #pragma unroll
        for (int k = 0; k < 4; ++k) {
            unsigned short us = __builtin_bit_cast(unsigned short, (f16)ws[k]);
            s_wp[q][p][k] = ((unsigned)us << 16) | us;
            s_idx[q][p][k] = is[k];
        }
    }
    __syncthreads();

    const int q = t >> 5;
    const int h = (t >> 2) & 7;
    const int l4 = t & 3;
    const uint4* vb4 = (const uint4*)(valh + (size_t)(b * 8 + h) * STOT * 32);
    const int*      ip = &s_idx[q][h * 12][0];
    const unsigned* wp = &s_wp[q][h * 12][0];
    float accf[8] = {};
    #pragma unroll
    for (int pp = 0; pp < 4; ++pp) {
        int ix[12]; unsigned ww[12]; uint4 v[12];
        #pragma unroll
        for (int k = 0; k < 12; ++k) { ix[k] = ip[pp * 12 + k]; ww[k] = wp[pp * 12 + k]; }
        #pragma unroll
        for (int k = 0; k < 12; ++k) v[k] = vb4[(size_t)ix[k] * 4 + l4];
        f16x2 a0 = (f16x2)(f16)0, a1 = a0, a2 = a0, a3 = a0;
        #pragma unroll
        for (int k = 0; k < 12; ++k) {
            f16x2 wv = __builtin_bit_cast(f16x2, ww[k]);
            a0 += wv * __builtin_bit_cast(f16x2, v[k].x);
            a1 += wv * __builtin_bit_cast(f16x2, v[k].y);
            a2 += wv * __builtin_bit_cast(f16x2, v[k].z);
            a3 += wv * __builtin_bit_cast(f16x2, v[k].w);
        }
        accf[0] += (float)a0[0]; accf[1] += (float)a0[1];
        accf[2] += (float)a1[0]; accf[3] += (float)a1[1];
        accf[4] += (float)a2[0]; accf[5] += (float)a2[1];
        accf[6] += (float)a3[0]; accf[7] += (float)a3[1];
    }
    f16x8 ob;
    #pragma unroll
    for (int c = 0; c < 8; ++c) ob[c] = (f16)accf[c];
    *(f16x8*)(out_h + (size_t)(bq0 + q) * 256 + h * 32 + l4 * 8) = ob;
}

// ---------------------------------------------------------------------------
extern "C" void kernel_launch(void* const* d_in, const int* in_sizes, int n_in,
                              void* d_out, int out_size, void* d_ws, size_t ws_size,
                              hipStream_t stream)
{
    const float* query  = (const float*)d_in[0];
    const float* feat0  = (const float*)d_in[1];
    const float* feat1  = (const float*)d_in[2];
    const float* feat2  = (const float*)d_in[3];
    const float* refp   = (const float*)d_in[4];
    const float* W_off  = (const float*)d_in[5];
    const float* b_off  = (const float*)d_in[6];
    const float* W_attn = (const float*)d_in[7];
    const float* b_attn = (const float*)d_in[8];
    const float* W_val  = (const float*)d_in[9];
    const float* b_val  = (const float*)d_in[10];
    const float* W_out  = (const float*)d_in[11];
    const float* b_out  = (const float*)d_in[12];
    float* out = (float*)d_out;

    // workspace (~67 MB)
    f16*   valh  = (f16*)d_ws;                               // MQ*256 fp16
    float* rawo  = (float*)(valh + (size_t)MQ * 256);        // MQ*192 f32
    f16*   attnh = (f16*)(rawo + (size_t)MQ * 192);          // MQ*96 fp16
    f16*   Af    = attnh + (size_t)MQ * 96;                  // MQ*256 fp16
    f16*   outh  = Af;                                       // reuse after gemm_vr
    f16*   Wvt   = Af + (size_t)MQ * 256;                    // 256*256
    f16*   Wot   = Wvt + 65536;
    f16*   Wch   = Wot + 65536;                              // 288*256
    float* bcat  = (float*)(Wch + 73728);

    dim3 blk(256);

    prep_all<<<dim3(263, 8, 5), blk, 0, stream>>>(feat0, feat1, feat2,
                                                  W_val, W_out, W_off, W_attn,
                                                  b_off, b_attn,
                                                  Af, Wvt, Wot, Wch, bcat);
    gemm_vr<<<dim3(5, 263), blk, 0, stream>>>(Af, query, Wvt, Wch, b_val, bcat,
                                              valh, rawo, attnh);
    sample_v6<<<dim3(MQ / 8), blk, 0, stream>>>(valh, rawo, attnh, refp, outh);
    gemm_o<<<dim3(2, 263), blk, 0, stream>>>(outh, Wot, b_out, out);
}

// Round 7
// 239.238 us; speedup vs baseline: 1.1990x; 1.0504x over previous
//
#include <hip/hip_runtime.h>
#include <math.h>

#define NH    8
#define DIM   256
#define NQ    8400
#define BATCH 4
#define STOT  8400
#define MQ    (BATCH * NQ)   // 33600

typedef _Float16 f16;
typedef __attribute__((ext_vector_type(2))) _Float16 f16x2;
typedef __attribute__((ext_vector_type(8))) _Float16 f16x8;
typedef __attribute__((ext_vector_type(8))) unsigned short u16x8;
typedef __attribute__((ext_vector_type(4))) float  f32x4;

// Async global->LDS, 16B per lane. LDS dest is wave-uniform base + lane*16,
// so lds_ptr must be computed as base + lane_slot*16 (CK-style addrspace cast).
static __device__ __forceinline__ void gl_lds16(const void* g, void* l) {
    __builtin_amdgcn_global_load_lds(
        (const __attribute__((address_space(1))) unsigned int*)g,
        (__attribute__((address_space(3))) unsigned int*)(unsigned int)(unsigned long long)l,
        16, 0, 0);
}

// ---------------------------------------------------------------------------
// Fused prep: z=0..3 feat transpose (3 levels concat) for batch z;
// z=4: weight transposes + bias concat; z=5: query fp32 -> fp16.
__global__ __launch_bounds__(256) void prep_all(
    const float* __restrict__ feat0, const float* __restrict__ feat1,
    const float* __restrict__ feat2, const float* __restrict__ query,
    const float* __restrict__ W_val, const float* __restrict__ W_out,
    const float* __restrict__ W_off, const float* __restrict__ W_attn,
    const float* __restrict__ b_off, const float* __restrict__ b_attn,
    f16* __restrict__ Af, f16* __restrict__ Qh,
    f16* __restrict__ Wvt, f16* __restrict__ Wot,
    f16* __restrict__ Wch, float* __restrict__ bcat)
{
    const int z = blockIdx.z;
    const int t = threadIdx.x;
    __shared__ float tile[32][33];
    const int c = t & 31, r = t >> 5;

    if (z == 5) {  // query conversion, 16 elems/thread
        size_t base = ((size_t)(blockIdx.x * 8 + blockIdx.y) * 256 + t) * 16;
        if (base < (size_t)MQ * 256) {
            #pragma unroll
            for (int i = 0; i < 2; ++i) {
                float4 q0 = *(const float4*)(query + base + i * 8);
                float4 q1 = *(const float4*)(query + base + i * 8 + 4);
                f16x8 hv;
                hv[0] = (f16)q0.x; hv[1] = (f16)q0.y; hv[2] = (f16)q0.z; hv[3] = (f16)q0.w;
                hv[4] = (f16)q1.x; hv[5] = (f16)q1.y; hv[6] = (f16)q1.z; hv[7] = (f16)q1.w;
                *(f16x8*)(Qh + base + i * 8) = hv;
            }
        }
        return;
    }

    if (z == 4) {
        const int xb = blockIdx.x;
        if (xb > 25) return;
        if (xb == 25) {
            if (blockIdx.y == 0)
                for (int i = t; i < 288; i += 256)
                    bcat[i] = (i < 192) ? b_off[i] : b_attn[i - 192];
            return;
        }
        const float* W; f16* oH; int Nw, n0, nb;
        if (xb < 8)       { W = W_val;  oH = Wvt; Nw = 256; n0 = 0;   nb = xb * 32; }
        else if (xb < 16) { W = W_out;  oH = Wot; Nw = 256; n0 = 0;   nb = (xb - 8) * 32; }
        else if (xb < 22) { W = W_off;  oH = Wch; Nw = 192; n0 = 0;   nb = (xb - 16) * 32; }
        else              { W = W_attn; oH = Wch; Nw = 96;  n0 = 192; nb = (xb - 22) * 32; }
        const int k0 = blockIdx.y * 32;
        #pragma unroll
        for (int i = 0; i < 4; ++i) {
            int k = k0 + r + i * 8, n = nb + c;
            tile[r + i * 8][c] = (n < Nw) ? W[(size_t)k * Nw + n] : 0.f;
        }
        __syncthreads();
        #pragma unroll
        for (int i = 0; i < 4; ++i) {
            int n = nb + r + i * 8, k = k0 + c;
            if (n < Nw)
                oH[(size_t)(n0 + n) * 256 + k] = (f16)tile[c][r + i * 8];
        }
        return;
    }

    const int b = z;
    const int s0 = blockIdx.x * 32, k0 = blockIdx.y * 32;
    if (s0 >= 8400) return;
    const float* f0b = feat0 + (size_t)b * 256 * 6400;
    const float* f1b = feat1 + (size_t)b * 256 * 1600;
    const float* f2b = feat2 + (size_t)b * 256 * 400;
    #pragma unroll
    for (int i = 0; i < 4; ++i) {
        int rr = r + i * 8;
        int s = s0 + c;
        float v = 0.f;
        if (s < 8400) {
            const float* fp; int S, sl;
            if (s < 6400)      { fp = f0b; S = 6400; sl = s; }
            else if (s < 8000) { fp = f1b; S = 1600; sl = s - 6400; }
            else               { fp = f2b; S = 400;  sl = s - 8000; }
            v = fp[(size_t)(k0 + rr) * S + sl];
        }
        tile[rr][c] = v;
    }
    __syncthreads();
    #pragma unroll
    for (int i = 0; i < 4; ++i) {
        int s = s0 + r + i * 8, k = k0 + c;
        if (s < 8400)
            Af[((size_t)b * 8400 + s) * 256 + k] = (f16)tile[c][r + i * 8];
    }
}

// ---------------------------------------------------------------------------
// m97-style GEMM core: global_load_lds(16B) staging into unpadded pitch-32
// LDS with XOR chunk swizzle (f(r)=(r&3)^((r>>2)&3)) so fragment ds_read_b128
// is <=2-way (free). Tile 128x128, BK=32, mfma_f32_16x16x32_f16.
// KIND 0: fused val (x<2) + raw (x>=2).  KIND 1: out projection.
template<int KIND>
__global__ __launch_bounds__(256) void gemm_glds(
    const f16* __restrict__ A0, const f16* __restrict__ A1,
    const f16* __restrict__ B0, const f16* __restrict__ B1,
    const float* __restrict__ bias0, const float* __restrict__ bias1,
    f16* __restrict__ valh, float* __restrict__ rawo, f16* __restrict__ attnh,
    float* __restrict__ Cf)
{
    __shared__ f16 Ah[128 * 32];
    __shared__ f16 Bs[128 * 32];

    const bool split = (KIND == 0) && (blockIdx.x >= 2);
    const int bn = split ? (blockIdx.x - 2) * 128 : blockIdx.x * 128;
    const int bm = blockIdx.y * 128;
    const int N = split ? 288 : 256;
    const f16* Ag = split ? A1 : A0;
    const f16* Bg = split ? B1 : B0;
    const float* bias = split ? bias1 : bias0;

    const int t = threadIdx.x;
    const int lane = t & 63, w = t >> 6;
    const int wm = (w & 1) * 64, wn = (w >> 1) * 64;
    const int l15 = lane & 15, quad = lane >> 4;

    // staging constants: slot s = i*256 + t; row = i*64 + (t>>2); q' = t&3;
    // loaded k-chunk = q' ^ f(row), f independent of i.
    const int fstage = ((t >> 2) & 3) ^ ((t >> 4) & 3);
    const int qs = (t & 3) ^ fstage;
    // fragment k-chunk position: quad ^ f(row), f(row) = (l15&3)^((l15>>2)&3)
    const int ffrag = (l15 & 3) ^ ((l15 >> 2) & 3);
    const int qf = quad ^ ffrag;

    f32x4 acc[4][4];
    #pragma unroll
    for (int i = 0; i < 4; ++i)
        #pragma unroll
        for (int j = 0; j < 4; ++j)
            acc[i][j] = (f32x4){0.f, 0.f, 0.f, 0.f};

    for (int k0 = 0; k0 < 256; k0 += 32) {
        #pragma unroll
        for (int i = 0; i < 2; ++i) {
            int row = i * 64 + (t >> 2);
            int slot = i * 256 + t;
            int gr = bm + row; if (gr > MQ - 1) gr = MQ - 1;
            gl_lds16(Ag + (size_t)gr * 256 + k0 + qs * 8, &Ah[slot * 8]);
            int gn = bn + row; if (gn > N - 1) gn = N - 1;
            gl_lds16(Bg + (size_t)gn * 256 + k0 + qs * 8, &Bs[slot * 8]);
        }
        __syncthreads();

        f16x8 af[4], bfv[4];
        #pragma unroll
        for (int mt = 0; mt < 4; ++mt)
            af[mt] = *(const f16x8*)&Ah[((wm + mt * 16 + l15) * 4 + qf) * 8];
        #pragma unroll
        for (int nt = 0; nt < 4; ++nt)
            bfv[nt] = *(const f16x8*)&Bs[((wn + nt * 16 + l15) * 4 + qf) * 8];
        #pragma unroll
        for (int mt = 0; mt < 4; ++mt)
            #pragma unroll
            for (int nt = 0; nt < 4; ++nt)
                acc[mt][nt] = __builtin_amdgcn_mfma_f32_16x16x32_f16(af[mt], bfv[nt], acc[mt][nt], 0, 0, 0);
        __syncthreads();
    }

    #pragma unroll
    for (int nt = 0; nt < 4; ++nt) {
        int col = bn + wn + nt * 16 + l15;
        float bv = (col < N) ? bias[col] : 0.f;
        #pragma unroll
        for (int mt = 0; mt < 4; ++mt) {
            int row0 = bm + wm + mt * 16 + quad * 4;
            #pragma unroll
            for (int r = 0; r < 4; ++r) {
                int row = row0 + r;
                if (row >= MQ || col >= N) continue;
                float v = acc[mt][nt][r] + bv;
                if (KIND == 1) {
                    Cf[(size_t)row * 256 + col] = v;
                } else if (!split) {
                    int bb = row / STOT, s = row - bb * STOT;
                    int h = col >> 5, c = col & 31;
                    valh[(((size_t)(bb * 8 + h)) * STOT + s) * 32 + c] = (f16)v;
                } else if (col < 192) {
                    rawo[(size_t)row * 192 + col] = v;
                } else {
                    attnh[(size_t)row * 96 + (col - 192)] = (f16)v;
                }
            }
        }
    }
}

// ---------------------------------------------------------------------------
// Sampler v6: packed-fp16 inner loop, weights pre-packed (w,w), fp16 accums
// flushed to fp32 every 12 corners. XCD-swizzled.
__global__ __launch_bounds__(256) void sample_v6(
    const f16* __restrict__ valh,        // [B*8][STOT][32] fp16
    const float* __restrict__ raw_off,   // [MQ][192]
    const f16* __restrict__ attnh,       // [MQ][96] fp16
    const float* __restrict__ refp,      // [MQ][2]
    f16* __restrict__ out_h)             // [MQ][256] fp16
{
    const int bx = blockIdx.x;
    const int xcd = bx & 7;
    const int b = xcd >> 1;
    const int qi = (bx >> 3) * 2 + (xcd & 1);
    const int bq0 = b * NQ + qi * 8;
    const int t = threadIdx.x;

    __shared__ int      s_idx[8][96][4];
    __shared__ unsigned s_wp[8][96][4];   // packed (w,w) f16x2
    __shared__ float    s_m[8][8];
    __shared__ float    s_inv[8][8];

    if (t < 64) {
        int q = t >> 3, h = t & 7;
        const f16* a = attnh + (size_t)(bq0 + q) * 96 + h * 12;
        float m = (float)a[0];
        #pragma unroll
        for (int j = 1; j < 12; ++j) m = fmaxf(m, (float)a[j]);
        float s = 0.f;
        #pragma unroll
        for (int j = 0; j < 12; ++j) s += expf((float)a[j] - m);
        s_m[q][h] = m;
        s_inv[q][h] = 1.f / s;
    }
    __syncthreads();

    for (int i = t; i < 768; i += 256) {
        int q = i / 96, p = i - q * 96;
        int h = p / 12, lp = p - h * 12, l = lp >> 2;
        const int dims[3]   = {80, 40, 20};
        const int bases_[3] = {0, 6400, 8000};
        int Wl = dims[l], base = bases_[l];
        float logit = (float)attnh[(size_t)(bq0 + q) * 96 + p];
        float aw = expf(logit - s_m[q][h]) * s_inv[q][h];
        size_t ro = (size_t)(bq0 + q) * 192 + h * 24 + lp * 2;
        float rawx = raw_off[ro], rawy = raw_off[ro + 1];
        float rx = refp[(size_t)(bq0 + q) * 2];
        float ry = refp[(size_t)(bq0 + q) * 2 + 1];
        float ix = (rx + tanhf(rawx) * 0.5f) * Wl - 0.5f;
        float iy = (ry + tanhf(rawy) * 0.5f) * Wl - 0.5f;
        float x0f = floorf(ix), y0f = floorf(iy);
        float fx = ix - x0f, fy = iy - y0f;
        int x0 = (int)x0f, y0 = (int)y0f;
        float w00 = (1.f - fx) * (1.f - fy) * aw;
        float w01 = fx * (1.f - fy) * aw;
        float w10 = (1.f - fx) * fy * aw;
        float w11 = fx * fy * aw;
        bool vx0 = (unsigned)x0 < (unsigned)Wl;
        bool vx1 = (unsigned)(x0 + 1) < (unsigned)Wl;
        bool vy0 = (unsigned)y0 < (unsigned)Wl;
        bool vy1 = (unsigned)(y0 + 1) < (unsigned)Wl;
        int row0 = base + y0 * Wl, row1 = row0 + Wl;
        float ws[4] = { vx0 && vy0 ? w00 : 0.f, vx1 && vy0 ? w01 : 0.f,
                        vx0 && vy1 ? w10 : 0.f, vx1 && vy1 ? w11 : 0.f };
        int   is[4] = { vx0 && vy0 ? row0 + x0 : 0, vx1 && vy0 ? row0 + x0 + 1 : 0,
                        vx0 && vy1 ? row1 + x0 : 0, vx1 && vy1 ? row1 + x0 + 1 : 0 };
        #pragma unroll
        for (int k = 0; k < 4; ++k) {
            unsigned short us = __builtin_bit_cast(unsigned short, (f16)ws[k]);
            s_wp[q][p][k] = ((unsigned)us << 16) | us;
            s_idx[q][p][k] = is[k];
        }
    }
    __syncthreads();

    const int q = t >> 5;
    const int h = (t >> 2) & 7;
    const int l4 = t & 3;
    const uint4* vb4 = (const uint4*)(valh + (size_t)(b * 8 + h) * STOT * 32);
    const int*      ip = &s_idx[q][h * 12][0];
    const unsigned* wp = &s_wp[q][h * 12][0];
    float accf[8] = {};
    #pragma unroll
    for (int pp = 0; pp < 4; ++pp) {
        int ix[12]; unsigned ww[12]; uint4 v[12];
        #pragma unroll
        for (int k = 0; k < 12; ++k) { ix[k] = ip[pp * 12 + k]; ww[k] = wp[pp * 12 + k]; }
        #pragma unroll
        for (int k = 0; k < 12; ++k) v[k] = vb4[(size_t)ix[k] * 4 + l4];
        f16x2 a0 = (f16x2)(f16)0, a1 = a0, a2 = a0, a3 = a0;
        #pragma unroll
        for (int k = 0; k < 12; ++k) {
            f16x2 wv = __builtin_bit_cast(f16x2, ww[k]);
            a0 += wv * __builtin_bit_cast(f16x2, v[k].x);
            a1 += wv * __builtin_bit_cast(f16x2, v[k].y);
            a2 += wv * __builtin_bit_cast(f16x2, v[k].z);
            a3 += wv * __builtin_bit_cast(f16x2, v[k].w);
        }
        accf[0] += (float)a0[0]; accf[1] += (float)a0[1];
        accf[2] += (float)a1[0]; accf[3] += (float)a1[1];
        accf[4] += (float)a2[0]; accf[5] += (float)a2[1];
        accf[6] += (float)a3[0]; accf[7] += (float)a3[1];
    }
    f16x8 ob;
    #pragma unroll
    for (int c = 0; c < 8; ++c) ob[c] = (f16)accf[c];
    *(f16x8*)(out_h + (size_t)(bq0 + q) * 256 + h * 32 + l4 * 8) = ob;
}

// ---------------------------------------------------------------------------
extern "C" void kernel_launch(void* const* d_in, const int* in_sizes, int n_in,
                              void* d_out, int out_size, void* d_ws, size_t ws_size,
                              hipStream_t stream)
{
    const float* query  = (const float*)d_in[0];
    const float* feat0  = (const float*)d_in[1];
    const float* feat1  = (const float*)d_in[2];
    const float* feat2  = (const float*)d_in[3];
    const float* refp   = (const float*)d_in[4];
    const float* W_off  = (const float*)d_in[5];
    const float* b_off  = (const float*)d_in[6];
    const float* W_attn = (const float*)d_in[7];
    const float* b_attn = (const float*)d_in[8];
    const float* W_val  = (const float*)d_in[9];
    const float* b_val  = (const float*)d_in[10];
    const float* W_out  = (const float*)d_in[11];
    const float* b_out  = (const float*)d_in[12];
    float* out = (float*)d_out;

    // workspace (~85 MB)
    f16*   valh  = (f16*)d_ws;                               // MQ*256 fp16
    float* rawo  = (float*)(valh + (size_t)MQ * 256);        // MQ*192 f32
    f16*   attnh = (f16*)(rawo + (size_t)MQ * 192);          // MQ*96 fp16
    f16*   Af    = attnh + (size_t)MQ * 96;                  // MQ*256 fp16
    f16*   outh  = Af;                                       // reuse after gemm_vr
    f16*   Qh    = Af + (size_t)MQ * 256;                    // MQ*256 fp16
    f16*   Wvt   = Qh + (size_t)MQ * 256;                    // 256*256
    f16*   Wot   = Wvt + 65536;
    f16*   Wch   = Wot + 65536;                              // 288*256
    float* bcat  = (float*)(Wch + 73728);

    dim3 blk(256);

    prep_all<<<dim3(263, 8, 6), blk, 0, stream>>>(feat0, feat1, feat2, query,
                                                  W_val, W_out, W_off, W_attn,
                                                  b_off, b_attn,
                                                  Af, Qh, Wvt, Wot, Wch, bcat);
    gemm_glds<0><<<dim3(5, 263), blk, 0, stream>>>(Af, Qh, Wvt, Wch, b_val, bcat,
                                                   valh, rawo, attnh, nullptr);
    sample_v6<<<dim3(MQ / 8), blk, 0, stream>>>(valh, rawo, attnh, refp, outh);
    gemm_glds<1><<<dim3(2, 263), blk, 0, stream>>>(outh, nullptr, Wot, nullptr,
                                                   b_out, nullptr,
                                                   nullptr, nullptr, nullptr, out);
}